// Round 4
// baseline (1155.408 us; speedup 1.0000x reference)
//
#include <hip/hip_runtime.h>

#define NN 100000      // N_NODES
#define NE 3200000     // N_EDGES
#define NF 128         // N_F
#define NH 128         // HIDDEN
#define NP 8           // N_PRED
#define NG 64          // N_GRAPHS

#define CS 16000       // bins per chunk (64 KB LDS as u32/f32)
#define NC 7           // ceil(100000/16000)
#define NW 64          // edge slices
#define ES (NE / NW)   // 50000 edges per slice

#define SCAN_B 1024
#define SCAN_NBLK 98   // ceil(100000/1024)

// ---------------- init: cnt, psum ----------------
__global__ void k_init(float* __restrict__ cnt, float* __restrict__ psum) {
    int i = blockIdx.x * blockDim.x + threadIdx.x;
    if (i < NG) cnt[i] = 0.0f;
    if (i < NG * NH) psum[i] = 0.0f;
}

// ---------------- row histogram: H[w][r] via LDS, no global atomics ----------------
__global__ __launch_bounds__(256) void k_hist(const int* __restrict__ row,
                                              unsigned* __restrict__ H) {
    __shared__ unsigned hist[CS];
    int w = blockIdx.x % NW, c = blockIdx.x / NW;
    int rbase = c * CS;
    int nb = (rbase + CS <= NN) ? CS : (NN - rbase);
    for (int i = threadIdx.x; i < nb; i += 256) hist[i] = 0u;
    __syncthreads();
    int e0 = w * ES;
    for (int e = e0 + threadIdx.x; e < e0 + ES; e += 256) {
        unsigned rr = (unsigned)(row[e] - rbase);
        if (rr < (unsigned)nb) atomicAdd(&hist[rr], 1u);
    }
    __syncthreads();
    for (int i = threadIdx.x; i < nb; i += 256) H[(size_t)w * NN + rbase + i] = hist[i];
}

// ---------------- weighted col histogram: Hd[w][c] via LDS ----------------
__global__ __launch_bounds__(256) void k_deg_hist(const int* __restrict__ col,
                                                  const float* __restrict__ wt,
                                                  float* __restrict__ Hd) {
    __shared__ float dh[CS];
    int w = blockIdx.x % NW, c = blockIdx.x / NW;
    int rbase = c * CS;
    int nb = (rbase + CS <= NN) ? CS : (NN - rbase);
    for (int i = threadIdx.x; i < nb; i += 256) dh[i] = 0.0f;
    __syncthreads();
    int e0 = w * ES;
    for (int e = e0 + threadIdx.x; e < e0 + ES; e += 256) {
        unsigned cc = (unsigned)(col[e] - rbase);
        if (cc < (unsigned)nb) atomicAdd(&dh[cc], wt[e]);
    }
    __syncthreads();
    for (int i = threadIdx.x; i < nb; i += 256) Hd[(size_t)w * NN + rbase + i] = dh[i];
}

// ---------------- per-graph node counts ----------------
__global__ void k_cnt(const int* __restrict__ batch, float* __restrict__ cnt) {
    __shared__ float c[NG];
    int t = threadIdx.x;
    if (t < NG) c[t] = 0.0f;
    __syncthreads();
    int i = blockIdx.x * blockDim.x + t;
    if (i < NN) atomicAdd(&c[batch[i]], 1.0f);
    __syncthreads();
    if (t < NG && c[t] != 0.0f) atomicAdd(&cnt[t], c[t]);
}

// ---------------- reduce slices: rcnt[r] = sum_w H, dinv[r] = rsqrt(1 + sum_w Hd) ----------------
__global__ void k_reduce(const unsigned* __restrict__ H, const float* __restrict__ Hd,
                         int* __restrict__ rcnt, float* __restrict__ dinv) {
    int r = blockIdx.x * blockDim.x + threadIdx.x;
    if (r >= NN) return;
    unsigned s = 0;
    float d = 1.0f;   // self-loop weight
#pragma unroll
    for (int w = 0; w < NW; ++w) {
        s += H[(size_t)w * NN + r];
        d += Hd[(size_t)w * NN + r];
    }
    rcnt[r] = (int)s;
    dinv[r] = rsqrtf(d);
}

// ---------------- scan pass 1 ----------------
__global__ __launch_bounds__(SCAN_B) void k_scan1(const int* __restrict__ rcnt,
                                                  int* __restrict__ px,
                                                  int* __restrict__ bsum) {
    __shared__ int s[SCAN_B];
    int t = threadIdx.x;
    int i = blockIdx.x * SCAN_B + t;
    int v = (i < NN) ? rcnt[i] : 0;
    s[t] = v;
    __syncthreads();
    for (int off = 1; off < SCAN_B; off <<= 1) {
        int x = (t >= off) ? s[t - off] : 0;
        __syncthreads();
        s[t] += x;
        __syncthreads();
    }
    px[i] = s[t] - v;
    if (t == SCAN_B - 1) bsum[blockIdx.x] = s[t];
}

// ---------------- scan pass 2 ----------------
__global__ void k_scan2(const int* __restrict__ bsum, int* __restrict__ bofs) {
    if (threadIdx.x == 0) {
        int acc = 0;
        for (int b = 0; b < SCAN_NBLK; ++b) { bofs[b] = acc; acc += bsum[b]; }
    }
}

// ---------------- scan pass 3: rowptr ----------------
__global__ void k_scan3(const int* __restrict__ px, const int* __restrict__ bofs,
                        int* __restrict__ rowptr) {
    int i = blockIdx.x * blockDim.x + threadIdx.x;
    if (i > NN) return;
    rowptr[i] = px[i] + bofs[i >> 10];
}

// ---------------- H -> per-(row,slice) base offsets (in place) ----------------
__global__ void k_base(const int* __restrict__ rowptr, unsigned* __restrict__ H) {
    int r = blockIdx.x * blockDim.x + threadIdx.x;
    if (r >= NN) return;
    unsigned acc = (unsigned)rowptr[r];
#pragma unroll
    for (int w = 0; w < NW; ++w) {
        unsigned v = H[(size_t)w * NN + r];
        H[(size_t)w * NN + r] = acc;
        acc += v;
    }
}

// ---------------- stable counting-sort scatter: pack[pos] = (src, norm) ----------------
__global__ __launch_bounds__(256) void k_sort(const int* __restrict__ row,
                                              const int* __restrict__ col,
                                              const float* __restrict__ wt,
                                              const unsigned* __restrict__ B,
                                              const float* __restrict__ dinv,
                                              float2* __restrict__ pack) {
    __shared__ unsigned basel[CS];
    int w = blockIdx.x % NW, c = blockIdx.x / NW;
    int rbase = c * CS;
    int nb = (rbase + CS <= NN) ? CS : (NN - rbase);
    for (int i = threadIdx.x; i < nb; i += 256)
        basel[i] = B[(size_t)w * NN + rbase + i];
    __syncthreads();
    int e0 = w * ES;
    for (int e = e0 + threadIdx.x; e < e0 + ES; e += 256) {
        int r = row[e];
        unsigned rr = (unsigned)(r - rbase);
        if (rr < (unsigned)nb) {
            unsigned pos = atomicAdd(&basel[rr], 1u);
            int cc = col[e];
            pack[pos] = make_float2(__int_as_float(cc), dinv[r] * wt[e] * dinv[cc]);
        }
    }
}

// ---------------- hop 1: Qa[n][g] = dinv^2*(batch[n]==g) + sum nrm*(batch[src]==g) ----------------
__global__ void k_q1_gather(const int* __restrict__ rowptr, const float2* __restrict__ pack,
                            const int* __restrict__ batch, const float* __restrict__ dinv,
                            float* __restrict__ Q) {
    int wid = (blockIdx.x * blockDim.x + threadIdx.x) >> 6;
    int lane = threadIdx.x & 63;
    if (wid >= NN) return;
    int beg = rowptr[wid], end = rowptr[wid + 1];
    float d = dinv[wid];
    float acc = (batch[wid] == lane) ? d * d : 0.0f;
    int e = beg;
    for (; e + 4 <= end; e += 4) {
        float2 p0 = pack[e], p1 = pack[e + 1], p2 = pack[e + 2], p3 = pack[e + 3];
        int b0 = batch[__float_as_int(p0.x)];
        int b1 = batch[__float_as_int(p1.x)];
        int b2 = batch[__float_as_int(p2.x)];
        int b3 = batch[__float_as_int(p3.x)];
        acc += (b0 == lane ? p0.y : 0.0f) + (b1 == lane ? p1.y : 0.0f)
             + (b2 == lane ? p2.y : 0.0f) + (b3 == lane ? p3.y : 0.0f);
    }
    for (; e < end; ++e) {
        float2 p = pack[e];
        acc += (batch[__float_as_int(p.x)] == lane) ? p.y : 0.0f;
    }
    Q[(wid << 6) + lane] = acc;
}

// ---------------- hops 2,3: Qout[n][g] = dinv^2*Qin[n][g] + sum nrm*Qin[src][g] ----------------
__global__ void k_hop_gather(const int* __restrict__ rowptr, const float2* __restrict__ pack,
                             const float* __restrict__ dinv, const float* __restrict__ Qin,
                             float* __restrict__ Qout) {
    int wid = (blockIdx.x * blockDim.x + threadIdx.x) >> 6;
    int lane = threadIdx.x & 63;
    if (wid >= NN) return;
    int beg = rowptr[wid], end = rowptr[wid + 1];
    float d = dinv[wid];
    float acc = d * d * Qin[(wid << 6) + lane];
    int e = beg;
    for (; e + 4 <= end; e += 4) {
        float2 p0 = pack[e], p1 = pack[e + 1], p2 = pack[e + 2], p3 = pack[e + 3];
        float q0 = Qin[(__float_as_int(p0.x) << 6) + lane];
        float q1 = Qin[(__float_as_int(p1.x) << 6) + lane];
        float q2 = Qin[(__float_as_int(p2.x) << 6) + lane];
        float q3 = Qin[(__float_as_int(p3.x) << 6) + lane];
        acc += p0.y * q0 + p1.y * q1 + p2.y * q2 + p3.y * q3;
    }
    for (; e < end; ++e) {
        float2 p = pack[e];
        acc += p.y * Qin[(__float_as_int(p.x) << 6) + lane];
    }
    Qout[(wid << 6) + lane] = acc;
}

// ---------------- psum[g][f] = sum_n Q3[n][g] * x[n][f] ----------------
__global__ __launch_bounds__(256) void k_pool(const float* __restrict__ Q,
                                              const float* __restrict__ x,
                                              float* __restrict__ psum) {
    __shared__ float q[NG];
    __shared__ float xv[NF];
    int t = threadIdx.x;
    int f0 = t & 31;
    int g8 = t >> 5;
    float acc[8][4] = {};
    for (int n = blockIdx.x; n < NN; n += gridDim.x) {
        if (t < 64) q[t] = Q[n * 64 + t];
        else if (t < 192) xv[t - 64] = x[n * 128 + (t - 64)];
        __syncthreads();
#pragma unroll
        for (int i = 0; i < 8; ++i) {
            float qv = q[g8 * 8 + i];
#pragma unroll
            for (int j = 0; j < 4; ++j)
                acc[i][j] += qv * xv[f0 + 32 * j];
        }
        __syncthreads();
    }
#pragma unroll
    for (int i = 0; i < 8; ++i)
#pragma unroll
        for (int j = 0; j < 4; ++j)
            atomicAdd(&psum[(g8 * 8 + i) * NF + f0 + 32 * j], acc[i][j]);
}

// ---------------- final: fold both linears ----------------
__global__ void k_final(const float* __restrict__ psum, const float* __restrict__ cnt,
                        const float* __restrict__ Wc, const float* __restrict__ bc,
                        const float* __restrict__ Wl, const float* __restrict__ bl,
                        float* __restrict__ out) {
    __shared__ float M[NP * NH];
    __shared__ float bias[NP];
    int t = threadIdx.x;
    for (int idx = t; idx < NP * NH; idx += 256) {
        int p = idx >> 7, f = idx & 127;
        float s = 0.0f;
        for (int h = 0; h < NH; ++h) s += Wl[p * NH + h] * Wc[h * NF + f];
        M[idx] = s;
    }
    if (t < NP) {
        float s = bl[t];
        for (int h = 0; h < NH; ++h) s += Wl[t * NH + h] * bc[h];
        bias[t] = s;
    }
    __syncthreads();
    for (int idx = t; idx < NG * NP; idx += 256) {
        int g = idx >> 3, p = idx & 7;
        float inv = 1.0f / fmaxf(cnt[g], 1.0f);
        float s = 0.0f;
        for (int f = 0; f < NF; ++f) s += psum[g * NF + f] * M[p * NH + f];
        out[idx] = s * inv + bias[p];
    }
}

extern "C" void kernel_launch(void* const* d_in, const int* in_sizes, int n_in,
                              void* d_out, int out_size, void* d_ws, size_t ws_size,
                              hipStream_t stream) {
    const float* x     = (const float*)d_in[0];
    const int*   ei    = (const int*)d_in[1];
    const float* ea    = (const float*)d_in[2];
    const int*   batch = (const int*)d_in[3];
    const float* Wc    = (const float*)d_in[4];
    const float* bc    = (const float*)d_in[5];
    const float* Wl    = (const float*)d_in[6];
    const float* bl    = (const float*)d_in[7];
    const int* row = ei;           // edge_index[0]
    const int* col = ei + NE;      // edge_index[1]
    float* out = (float*)d_out;

    // ---- workspace (~77.7 MB, same footprint as proven R2 layout) ----
    // H aliases Qa (both 25.6 MB, dead before q1_gather writes Qa).
    // Hd aliases Qb (dead after k_reduce, before hop2 writes Qb).
    // scan scratch aliases pack (dead before k_sort writes pack).
    float* ws     = (float*)d_ws;
    float*  dinv   = ws;                          // NN
    int*    rowptr = (int*)(dinv + NN);           // NN+2
    float*  cnt    = (float*)(rowptr + NN + 2);   // NG
    float*  psum   = cnt + NG;                    // NG*NH
    float2* pack   = (float2*)(psum + NG * NH);   // NE float2
    float*  Qb     = (float*)(pack + NE);         // NN*64
    float*  Qa     = Qb + (size_t)NN * NG;        // NN*64
    unsigned* H  = (unsigned*)Qa;                 // NW*NN (exactly Qa-sized)
    float*    Hd = Qb;                            // NW*NN (exactly Qb-sized)
    int* rcnt = (int*)pack;                       // NN
    int* px   = rcnt + SCAN_NBLK * SCAN_B;        // SCAN_NBLK*SCAN_B
    int* bsum = px + SCAN_NBLK * SCAN_B;          // SCAN_NBLK
    int* bofs = bsum + SCAN_NBLK;                 // SCAN_NBLK

    const int B = 256;
    int gN  = (NN + B - 1) / B;                          // 391
    int gCW = NC * NW;                                   // 448
    int gW  = (int)(((long long)NN * 64 + B - 1) / B);   // 25000

    k_init<<<(NG * NH + B - 1) / B, B, 0, stream>>>(cnt, psum);
    k_hist<<<gCW, B, 0, stream>>>(row, H);
    k_deg_hist<<<gCW, B, 0, stream>>>(col, ea, Hd);
    k_cnt<<<gN, B, 0, stream>>>(batch, cnt);
    k_reduce<<<gN, B, 0, stream>>>(H, Hd, rcnt, dinv);

    k_scan1<<<SCAN_NBLK, SCAN_B, 0, stream>>>(rcnt, px, bsum);
    k_scan2<<<1, 64, 0, stream>>>(bsum, bofs);
    k_scan3<<<(NN + 1 + SCAN_B - 1) / SCAN_B, SCAN_B, 0, stream>>>(px, bofs, rowptr);
    k_base<<<gN, B, 0, stream>>>(rowptr, H);
    k_sort<<<gCW, B, 0, stream>>>(row, col, ea, H, dinv, pack);

    k_q1_gather<<<gW, B, 0, stream>>>(rowptr, pack, batch, dinv, Qa);
    k_hop_gather<<<gW, B, 0, stream>>>(rowptr, pack, dinv, Qa, Qb);
    k_hop_gather<<<gW, B, 0, stream>>>(rowptr, pack, dinv, Qb, Qa);

    k_pool<<<256, B, 0, stream>>>(Qa, x, psum);
    k_final<<<1, B, 0, stream>>>(psum, cnt, Wc, bc, Wl, bl, out);
}

// Round 5
// 1024.594 us; speedup vs baseline: 1.1277x; 1.1277x over previous
//
#include <hip/hip_runtime.h>

#define NN 100000      // N_NODES
#define NE 3200000     // N_EDGES
#define NF 128         // N_F
#define NH 128         // HIDDEN
#define NP 8           // N_PRED
#define NG 64          // N_GRAPHS

#define CS 16000       // bins per chunk (64 KB LDS as u32/f32)
#define NC 7           // ceil(100000/16000)
#define NW 64          // edge slices
#define ES (NE / NW)   // 50000 edges per slice

#define PT 64          // k_pool node tile

#define SCAN_B 1024
#define SCAN_NBLK 98   // ceil(100000/1024)

// ---------------- init: cnt, psum ----------------
__global__ void k_init(float* __restrict__ cnt, float* __restrict__ psum) {
    int i = blockIdx.x * blockDim.x + threadIdx.x;
    if (i < NG) cnt[i] = 0.0f;
    if (i < NG * NH) psum[i] = 0.0f;
}

// ---------------- row histogram: H[w][r] via LDS, no global atomics ----------------
__global__ __launch_bounds__(256) void k_hist(const int* __restrict__ row,
                                              unsigned* __restrict__ H) {
    __shared__ unsigned hist[CS];
    int w = blockIdx.x % NW, c = blockIdx.x / NW;
    int rbase = c * CS;
    int nb = (rbase + CS <= NN) ? CS : (NN - rbase);
    for (int i = threadIdx.x; i < nb; i += 256) hist[i] = 0u;
    __syncthreads();
    int e0 = w * ES;
    for (int e = e0 + threadIdx.x; e < e0 + ES; e += 256) {
        unsigned rr = (unsigned)(row[e] - rbase);
        if (rr < (unsigned)nb) atomicAdd(&hist[rr], 1u);
    }
    __syncthreads();
    for (int i = threadIdx.x; i < nb; i += 256) H[(size_t)w * NN + rbase + i] = hist[i];
}

// ---------------- weighted col histogram: Hd[w][c] via LDS ----------------
__global__ __launch_bounds__(256) void k_deg_hist(const int* __restrict__ col,
                                                  const float* __restrict__ wt,
                                                  float* __restrict__ Hd) {
    __shared__ float dh[CS];
    int w = blockIdx.x % NW, c = blockIdx.x / NW;
    int rbase = c * CS;
    int nb = (rbase + CS <= NN) ? CS : (NN - rbase);
    for (int i = threadIdx.x; i < nb; i += 256) dh[i] = 0.0f;
    __syncthreads();
    int e0 = w * ES;
    for (int e = e0 + threadIdx.x; e < e0 + ES; e += 256) {
        unsigned cc = (unsigned)(col[e] - rbase);
        if (cc < (unsigned)nb) atomicAdd(&dh[cc], wt[e]);
    }
    __syncthreads();
    for (int i = threadIdx.x; i < nb; i += 256) Hd[(size_t)w * NN + rbase + i] = dh[i];
}

// ---------------- per-graph node counts ----------------
__global__ void k_cnt(const int* __restrict__ batch, float* __restrict__ cnt) {
    __shared__ float c[NG];
    int t = threadIdx.x;
    if (t < NG) c[t] = 0.0f;
    __syncthreads();
    int i = blockIdx.x * blockDim.x + t;
    if (i < NN) atomicAdd(&c[batch[i]], 1.0f);
    __syncthreads();
    if (t < NG && c[t] != 0.0f) atomicAdd(&cnt[t], c[t]);
}

// ---------------- reduce slices: rcnt[r] = sum_w H, dinv[r] = rsqrt(1 + sum_w Hd) ----------------
__global__ void k_reduce(const unsigned* __restrict__ H, const float* __restrict__ Hd,
                         int* __restrict__ rcnt, float* __restrict__ dinv) {
    int r = blockIdx.x * blockDim.x + threadIdx.x;
    if (r >= NN) return;
    unsigned s = 0;
    float d = 1.0f;   // self-loop weight
#pragma unroll
    for (int w = 0; w < NW; ++w) {
        s += H[(size_t)w * NN + r];
        d += Hd[(size_t)w * NN + r];
    }
    rcnt[r] = (int)s;
    dinv[r] = rsqrtf(d);
}

// ---------------- scan pass 1 ----------------
__global__ __launch_bounds__(SCAN_B) void k_scan1(const int* __restrict__ rcnt,
                                                  int* __restrict__ px,
                                                  int* __restrict__ bsum) {
    __shared__ int s[SCAN_B];
    int t = threadIdx.x;
    int i = blockIdx.x * SCAN_B + t;
    int v = (i < NN) ? rcnt[i] : 0;
    s[t] = v;
    __syncthreads();
    for (int off = 1; off < SCAN_B; off <<= 1) {
        int x = (t >= off) ? s[t - off] : 0;
        __syncthreads();
        s[t] += x;
        __syncthreads();
    }
    px[i] = s[t] - v;
    if (t == SCAN_B - 1) bsum[blockIdx.x] = s[t];
}

// ---------------- scan pass 2 ----------------
__global__ void k_scan2(const int* __restrict__ bsum, int* __restrict__ bofs) {
    if (threadIdx.x == 0) {
        int acc = 0;
        for (int b = 0; b < SCAN_NBLK; ++b) { bofs[b] = acc; acc += bsum[b]; }
    }
}

// ---------------- scan pass 3: rowptr ----------------
__global__ void k_scan3(const int* __restrict__ px, const int* __restrict__ bofs,
                        int* __restrict__ rowptr) {
    int i = blockIdx.x * blockDim.x + threadIdx.x;
    if (i > NN) return;
    rowptr[i] = px[i] + bofs[i >> 10];
}

// ---------------- H -> per-(row,slice) base offsets (in place) ----------------
__global__ void k_base(const int* __restrict__ rowptr, unsigned* __restrict__ H) {
    int r = blockIdx.x * blockDim.x + threadIdx.x;
    if (r >= NN) return;
    unsigned acc = (unsigned)rowptr[r];
#pragma unroll
    for (int w = 0; w < NW; ++w) {
        unsigned v = H[(size_t)w * NN + r];
        H[(size_t)w * NN + r] = acc;
        acc += v;
    }
}

// ---------------- stable counting-sort scatter: pack[pos] = (src, norm) ----------------
__global__ __launch_bounds__(256) void k_sort(const int* __restrict__ row,
                                              const int* __restrict__ col,
                                              const float* __restrict__ wt,
                                              const unsigned* __restrict__ B,
                                              const float* __restrict__ dinv,
                                              float2* __restrict__ pack) {
    __shared__ unsigned basel[CS];
    int w = blockIdx.x % NW, c = blockIdx.x / NW;
    int rbase = c * CS;
    int nb = (rbase + CS <= NN) ? CS : (NN - rbase);
    for (int i = threadIdx.x; i < nb; i += 256)
        basel[i] = B[(size_t)w * NN + rbase + i];
    __syncthreads();
    int e0 = w * ES;
    for (int e = e0 + threadIdx.x; e < e0 + ES; e += 256) {
        int r = row[e];
        unsigned rr = (unsigned)(r - rbase);
        if (rr < (unsigned)nb) {
            unsigned pos = atomicAdd(&basel[rr], 1u);
            int cc = col[e];
            pack[pos] = make_float2(__int_as_float(cc), dinv[r] * wt[e] * dinv[cc]);
        }
    }
}

// ---------------- hop 1: Qa[n][g] = dinv^2*(batch[n]==g) + sum nrm*(batch[src]==g) ----------------
__global__ void k_q1_gather(const int* __restrict__ rowptr, const float2* __restrict__ pack,
                            const int* __restrict__ batch, const float* __restrict__ dinv,
                            float* __restrict__ Q) {
    int wid = (blockIdx.x * blockDim.x + threadIdx.x) >> 6;
    int lane = threadIdx.x & 63;
    if (wid >= NN) return;
    int beg = rowptr[wid], end = rowptr[wid + 1];
    float d = dinv[wid];
    float acc = (batch[wid] == lane) ? d * d : 0.0f;
    int e = beg;
    for (; e + 4 <= end; e += 4) {
        float2 p0 = pack[e], p1 = pack[e + 1], p2 = pack[e + 2], p3 = pack[e + 3];
        int b0 = batch[__float_as_int(p0.x)];
        int b1 = batch[__float_as_int(p1.x)];
        int b2 = batch[__float_as_int(p2.x)];
        int b3 = batch[__float_as_int(p3.x)];
        acc += (b0 == lane ? p0.y : 0.0f) + (b1 == lane ? p1.y : 0.0f)
             + (b2 == lane ? p2.y : 0.0f) + (b3 == lane ? p3.y : 0.0f);
    }
    for (; e < end; ++e) {
        float2 p = pack[e];
        acc += (batch[__float_as_int(p.x)] == lane) ? p.y : 0.0f;
    }
    Q[(wid << 6) + lane] = acc;
}

// ---------------- hops 2,3: Qout[n][g] = dinv^2*Qin[n][g] + sum nrm*Qin[src][g] ----------------
__global__ void k_hop_gather(const int* __restrict__ rowptr, const float2* __restrict__ pack,
                             const float* __restrict__ dinv, const float* __restrict__ Qin,
                             float* __restrict__ Qout) {
    int wid = (blockIdx.x * blockDim.x + threadIdx.x) >> 6;
    int lane = threadIdx.x & 63;
    if (wid >= NN) return;
    int beg = rowptr[wid], end = rowptr[wid + 1];
    float d = dinv[wid];
    float acc = d * d * Qin[(wid << 6) + lane];
    int e = beg;
    for (; e + 4 <= end; e += 4) {
        float2 p0 = pack[e], p1 = pack[e + 1], p2 = pack[e + 2], p3 = pack[e + 3];
        float q0 = Qin[(__float_as_int(p0.x) << 6) + lane];
        float q1 = Qin[(__float_as_int(p1.x) << 6) + lane];
        float q2 = Qin[(__float_as_int(p2.x) << 6) + lane];
        float q3 = Qin[(__float_as_int(p3.x) << 6) + lane];
        acc += p0.y * q0 + p1.y * q1 + p2.y * q2 + p3.y * q3;
    }
    for (; e < end; ++e) {
        float2 p = pack[e];
        acc += p.y * Qin[(__float_as_int(p.x) << 6) + lane];
    }
    Qout[(wid << 6) + lane] = acc;
}

// ---------------- psum[g][f] = sum_n Q3[n][g] * x[n][f]  (tiled, 64 nodes/iter) ----------------
__global__ __launch_bounds__(256) void k_pool(const float* __restrict__ Q,
                                              const float* __restrict__ x,
                                              float* __restrict__ psum) {
    __shared__ float qs[PT * NG];   // 16 KB
    __shared__ float xs[PT * NF];   // 32 KB
    int t = threadIdx.x;
    int f4 = (t & 31) << 2;    // 0,4,...,124 (contiguous 4 features -> ds_read_b128)
    int g0 = (t >> 5) << 3;    // 0,8,...,56  (8 graphs -> 2x ds_read_b128 broadcast)
    float4 acc[8];
#pragma unroll
    for (int i = 0; i < 8; ++i) acc[i] = make_float4(0.f, 0.f, 0.f, 0.f);

    const int NT = (NN + PT - 1) / PT;   // 1563
    for (int tile = blockIdx.x; tile < NT; tile += gridDim.x) {
        int n0 = tile * PT;
        int nt = min(PT, NN - n0);
        const float4* Q4 = (const float4*)(Q + (size_t)n0 * NG);
        const float4* X4 = (const float4*)(x + (size_t)n0 * NF);
        float4* qs4 = (float4*)qs;
        float4* xs4 = (float4*)xs;
        for (int i = t; i < nt * (NG / 4); i += 256) qs4[i] = Q4[i];
        for (int i = t; i < nt * (NF / 4); i += 256) xs4[i] = X4[i];
        __syncthreads();
        for (int n = 0; n < nt; ++n) {
            float4 xv = *(const float4*)&xs[n * NF + f4];
            float4 qa = *(const float4*)&qs[n * NG + g0];
            float4 qb = *(const float4*)&qs[n * NG + g0 + 4];
            float qv[8] = {qa.x, qa.y, qa.z, qa.w, qb.x, qb.y, qb.z, qb.w};
#pragma unroll
            for (int i = 0; i < 8; ++i) {
                acc[i].x += qv[i] * xv.x;
                acc[i].y += qv[i] * xv.y;
                acc[i].z += qv[i] * xv.z;
                acc[i].w += qv[i] * xv.w;
            }
        }
        __syncthreads();
    }
#pragma unroll
    for (int i = 0; i < 8; ++i) {
        atomicAdd(&psum[(g0 + i) * NF + f4 + 0], acc[i].x);
        atomicAdd(&psum[(g0 + i) * NF + f4 + 1], acc[i].y);
        atomicAdd(&psum[(g0 + i) * NF + f4 + 2], acc[i].z);
        atomicAdd(&psum[(g0 + i) * NF + f4 + 3], acc[i].w);
    }
}

// ---------------- final: fold both linears ----------------
__global__ void k_final(const float* __restrict__ psum, const float* __restrict__ cnt,
                        const float* __restrict__ Wc, const float* __restrict__ bc,
                        const float* __restrict__ Wl, const float* __restrict__ bl,
                        float* __restrict__ out) {
    __shared__ float M[NP * NH];
    __shared__ float bias[NP];
    int t = threadIdx.x;
    for (int idx = t; idx < NP * NH; idx += 256) {
        int p = idx >> 7, f = idx & 127;
        float s = 0.0f;
        for (int h = 0; h < NH; ++h) s += Wl[p * NH + h] * Wc[h * NF + f];
        M[idx] = s;
    }
    if (t < NP) {
        float s = bl[t];
        for (int h = 0; h < NH; ++h) s += Wl[t * NH + h] * bc[h];
        bias[t] = s;
    }
    __syncthreads();
    for (int idx = t; idx < NG * NP; idx += 256) {
        int g = idx >> 3, p = idx & 7;
        float inv = 1.0f / fmaxf(cnt[g], 1.0f);
        float s = 0.0f;
        for (int f = 0; f < NF; ++f) s += psum[g * NF + f] * M[p * NH + f];
        out[idx] = s * inv + bias[p];
    }
}

extern "C" void kernel_launch(void* const* d_in, const int* in_sizes, int n_in,
                              void* d_out, int out_size, void* d_ws, size_t ws_size,
                              hipStream_t stream) {
    const float* x     = (const float*)d_in[0];
    const int*   ei    = (const int*)d_in[1];
    const float* ea    = (const float*)d_in[2];
    const int*   batch = (const int*)d_in[3];
    const float* Wc    = (const float*)d_in[4];
    const float* bc    = (const float*)d_in[5];
    const float* Wl    = (const float*)d_in[6];
    const float* bl    = (const float*)d_in[7];
    const int* row = ei;           // edge_index[0]
    const int* col = ei + NE;      // edge_index[1]
    float* out = (float*)d_out;

    // ---- workspace (~77.7 MB) ----
    // H aliases Qa; Hd aliases Qb; scan scratch aliases pack (all dead before
    // their alias partner is first written).
    float* ws     = (float*)d_ws;
    float*  dinv   = ws;                          // NN
    int*    rowptr = (int*)(dinv + NN);           // NN+2
    float*  cnt    = (float*)(rowptr + NN + 2);   // NG
    float*  psum   = cnt + NG;                    // NG*NH
    float2* pack   = (float2*)(psum + NG * NH);   // NE float2
    float*  Qb     = (float*)(pack + NE);         // NN*64
    float*  Qa     = Qb + (size_t)NN * NG;        // NN*64
    unsigned* H  = (unsigned*)Qa;                 // NW*NN
    float*    Hd = Qb;                            // NW*NN
    int* rcnt = (int*)pack;                       // NN
    int* px   = rcnt + SCAN_NBLK * SCAN_B;        // SCAN_NBLK*SCAN_B
    int* bsum = px + SCAN_NBLK * SCAN_B;          // SCAN_NBLK
    int* bofs = bsum + SCAN_NBLK;                 // SCAN_NBLK

    const int B = 256;
    int gN  = (NN + B - 1) / B;                          // 391
    int gCW = NC * NW;                                   // 448
    int gW  = (int)(((long long)NN * 64 + B - 1) / B);   // 25000

    k_init<<<(NG * NH + B - 1) / B, B, 0, stream>>>(cnt, psum);
    k_hist<<<gCW, B, 0, stream>>>(row, H);
    k_deg_hist<<<gCW, B, 0, stream>>>(col, ea, Hd);
    k_cnt<<<gN, B, 0, stream>>>(batch, cnt);
    k_reduce<<<gN, B, 0, stream>>>(H, Hd, rcnt, dinv);

    k_scan1<<<SCAN_NBLK, SCAN_B, 0, stream>>>(rcnt, px, bsum);
    k_scan2<<<1, 64, 0, stream>>>(bsum, bofs);
    k_scan3<<<(NN + 1 + SCAN_B - 1) / SCAN_B, SCAN_B, 0, stream>>>(px, bofs, rowptr);
    k_base<<<gN, B, 0, stream>>>(rowptr, H);
    k_sort<<<gCW, B, 0, stream>>>(row, col, ea, H, dinv, pack);

    k_q1_gather<<<gW, B, 0, stream>>>(rowptr, pack, batch, dinv, Qa);
    k_hop_gather<<<gW, B, 0, stream>>>(rowptr, pack, dinv, Qa, Qb);
    k_hop_gather<<<gW, B, 0, stream>>>(rowptr, pack, dinv, Qb, Qa);

    k_pool<<<512, B, 0, stream>>>(Qa, x, psum);
    k_final<<<1, B, 0, stream>>>(psum, cnt, Wc, bc, Wl, bl, out);
}

// Round 6
// 814.511 us; speedup vs baseline: 1.4185x; 1.2579x over previous
//
#include <hip/hip_runtime.h>

#define NN 100000      // N_NODES
#define NE 3200000     // N_EDGES
#define NF 128         // N_F
#define NH 128         // HIDDEN
#define NP 8           // N_PRED
#define NG 64          // N_GRAPHS

#define CS 16000       // bins per chunk (64 KB LDS as u32/f32)
#define NC 7           // ceil(100000/16000)
#define NW 64          // edge slices
#define ES (NE / NW)   // 50000 edges per slice (divisible by 8)

#define PT 64          // k_pool node tile

#define SCAN_B 1024
#define SCAN_NBLK 98   // ceil(100000/1024)

// ---------------- init: cnt, psum ----------------
__global__ void k_init(float* __restrict__ cnt, float* __restrict__ psum) {
    int i = blockIdx.x * blockDim.x + threadIdx.x;
    if (i < NG) cnt[i] = 0.0f;
    if (i < NG * NH) psum[i] = 0.0f;
}

// ---------------- row histogram: H[w][r] via LDS, 8-edge vector loads ----------------
__global__ __launch_bounds__(256) void k_hist(const int* __restrict__ row,
                                              unsigned* __restrict__ H) {
    __shared__ unsigned hist[CS];
    int w = blockIdx.x % NW, c = blockIdx.x / NW;
    int rbase = c * CS;
    int nb = (rbase + CS <= NN) ? CS : (NN - rbase);
    for (int i = threadIdx.x; i < nb; i += 256) hist[i] = 0u;
    __syncthreads();
    const int4* r4 = (const int4*)(row + (size_t)w * ES);
    for (int i = threadIdx.x; i < ES / 8; i += 256) {
        int4 a = r4[2 * i], b = r4[2 * i + 1];
        int rs[8] = {a.x, a.y, a.z, a.w, b.x, b.y, b.z, b.w};
#pragma unroll
        for (int j = 0; j < 8; ++j) {
            unsigned rr = (unsigned)(rs[j] - rbase);
            if (rr < (unsigned)nb) atomicAdd(&hist[rr], 1u);
        }
    }
    __syncthreads();
    for (int i = threadIdx.x; i < nb; i += 256) H[(size_t)w * NN + rbase + i] = hist[i];
}

// ---------------- weighted col histogram: Hd[w][c] via LDS, vector loads ----------------
__global__ __launch_bounds__(256) void k_deg_hist(const int* __restrict__ col,
                                                  const float* __restrict__ wt,
                                                  float* __restrict__ Hd) {
    __shared__ float dh[CS];
    int w = blockIdx.x % NW, c = blockIdx.x / NW;
    int rbase = c * CS;
    int nb = (rbase + CS <= NN) ? CS : (NN - rbase);
    for (int i = threadIdx.x; i < nb; i += 256) dh[i] = 0.0f;
    __syncthreads();
    const int4*   c4 = (const int4*)(col + (size_t)w * ES);
    const float4* w4 = (const float4*)(wt + (size_t)w * ES);
    for (int i = threadIdx.x; i < ES / 8; i += 256) {
        int4 a = c4[2 * i], b = c4[2 * i + 1];
        float4 wa = w4[2 * i], wb = w4[2 * i + 1];
        int cc[8] = {a.x, a.y, a.z, a.w, b.x, b.y, b.z, b.w};
        float ww[8] = {wa.x, wa.y, wa.z, wa.w, wb.x, wb.y, wb.z, wb.w};
#pragma unroll
        for (int j = 0; j < 8; ++j) {
            unsigned rr = (unsigned)(cc[j] - rbase);
            if (rr < (unsigned)nb) atomicAdd(&dh[rr], ww[j]);
        }
    }
    __syncthreads();
    for (int i = threadIdx.x; i < nb; i += 256) Hd[(size_t)w * NN + rbase + i] = dh[i];
}

// ---------------- per-graph node counts ----------------
__global__ void k_cnt(const int* __restrict__ batch, float* __restrict__ cnt) {
    __shared__ float c[NG];
    int t = threadIdx.x;
    if (t < NG) c[t] = 0.0f;
    __syncthreads();
    int i = blockIdx.x * blockDim.x + t;
    if (i < NN) atomicAdd(&c[batch[i]], 1.0f);
    __syncthreads();
    if (t < NG && c[t] != 0.0f) atomicAdd(&cnt[t], c[t]);
}

// ---------------- reduce slices: rcnt[r] = sum_w H, dinv[r] = rsqrt(1 + sum_w Hd) ----------------
__global__ void k_reduce(const unsigned* __restrict__ H, const float* __restrict__ Hd,
                         int* __restrict__ rcnt, float* __restrict__ dinv) {
    int r = blockIdx.x * blockDim.x + threadIdx.x;
    if (r >= NN) return;
    unsigned s = 0;
    float d = 1.0f;   // self-loop weight
#pragma unroll
    for (int w = 0; w < NW; ++w) {
        s += H[(size_t)w * NN + r];
        d += Hd[(size_t)w * NN + r];
    }
    rcnt[r] = (int)s;
    dinv[r] = rsqrtf(d);
}

// ---------------- scan pass 1 ----------------
__global__ __launch_bounds__(SCAN_B) void k_scan1(const int* __restrict__ rcnt,
                                                  int* __restrict__ px,
                                                  int* __restrict__ bsum) {
    __shared__ int s[SCAN_B];
    int t = threadIdx.x;
    int i = blockIdx.x * SCAN_B + t;
    int v = (i < NN) ? rcnt[i] : 0;
    s[t] = v;
    __syncthreads();
    for (int off = 1; off < SCAN_B; off <<= 1) {
        int x = (t >= off) ? s[t - off] : 0;
        __syncthreads();
        s[t] += x;
        __syncthreads();
    }
    px[i] = s[t] - v;
    if (t == SCAN_B - 1) bsum[blockIdx.x] = s[t];
}

// ---------------- scan pass 2 ----------------
__global__ void k_scan2(const int* __restrict__ bsum, int* __restrict__ bofs) {
    if (threadIdx.x == 0) {
        int acc = 0;
        for (int b = 0; b < SCAN_NBLK; ++b) { bofs[b] = acc; acc += bsum[b]; }
    }
}

// ---------------- scan pass 3: rowptr ----------------
__global__ void k_scan3(const int* __restrict__ px, const int* __restrict__ bofs,
                        int* __restrict__ rowptr) {
    int i = blockIdx.x * blockDim.x + threadIdx.x;
    if (i > NN) return;
    rowptr[i] = px[i] + bofs[i >> 10];
}

// ---------------- H -> per-(row,slice) base offsets (in place) ----------------
__global__ void k_base(const int* __restrict__ rowptr, unsigned* __restrict__ H) {
    int r = blockIdx.x * blockDim.x + threadIdx.x;
    if (r >= NN) return;
    unsigned acc = (unsigned)rowptr[r];
#pragma unroll
    for (int w = 0; w < NW; ++w) {
        unsigned v = H[(size_t)w * NN + r];
        H[(size_t)w * NN + r] = acc;
        acc += v;
    }
}

// ---------------- stable counting-sort scatter, vector loads ----------------
__global__ __launch_bounds__(256) void k_sort(const int* __restrict__ row,
                                              const int* __restrict__ col,
                                              const float* __restrict__ wt,
                                              const unsigned* __restrict__ B,
                                              const float* __restrict__ dinv,
                                              float2* __restrict__ pack) {
    __shared__ unsigned basel[CS];
    int w = blockIdx.x % NW, c = blockIdx.x / NW;
    int rbase = c * CS;
    int nb = (rbase + CS <= NN) ? CS : (NN - rbase);
    for (int i = threadIdx.x; i < nb; i += 256)
        basel[i] = B[(size_t)w * NN + rbase + i];
    __syncthreads();
    const int4*   r4 = (const int4*)(row + (size_t)w * ES);
    const int4*   c4 = (const int4*)(col + (size_t)w * ES);
    const float4* w4 = (const float4*)(wt + (size_t)w * ES);
    for (int i = threadIdx.x; i < ES / 8; i += 256) {
        int4 ra = r4[2 * i], rb = r4[2 * i + 1];
        int4 ca = c4[2 * i], cb = c4[2 * i + 1];
        float4 wa = w4[2 * i], wb = w4[2 * i + 1];
        int rs[8] = {ra.x, ra.y, ra.z, ra.w, rb.x, rb.y, rb.z, rb.w};
        int cs[8] = {ca.x, ca.y, ca.z, ca.w, cb.x, cb.y, cb.z, cb.w};
        float ww[8] = {wa.x, wa.y, wa.z, wa.w, wb.x, wb.y, wb.z, wb.w};
#pragma unroll
        for (int j = 0; j < 8; ++j) {
            unsigned rr = (unsigned)(rs[j] - rbase);
            if (rr < (unsigned)nb) {
                unsigned pos = atomicAdd(&basel[rr], 1u);
                pack[pos] = make_float2(__int_as_float(cs[j]),
                                        dinv[rs[j]] * ww[j] * dinv[cs[j]]);
            }
        }
    }
}

// ---------------- hop 1: Qa[n][g] = dinv^2*(batch[n]==g) + sum nrm*(batch[src]==g) ----------------
__global__ void k_q1_gather(const int* __restrict__ rowptr, const float2* __restrict__ pack,
                            const int* __restrict__ batch, const float* __restrict__ dinv,
                            float* __restrict__ Q) {
    int wid = (blockIdx.x * blockDim.x + threadIdx.x) >> 6;
    int lane = threadIdx.x & 63;
    if (wid >= NN) return;
    int beg = rowptr[wid], end = rowptr[wid + 1];
    float d = dinv[wid];
    float acc = (batch[wid] == lane) ? d * d : 0.0f;
    int e = beg;
    for (; e + 8 <= end; e += 8) {
        float2 p[8];
#pragma unroll
        for (int j = 0; j < 8; ++j) p[j] = pack[e + j];
        int b[8];
#pragma unroll
        for (int j = 0; j < 8; ++j) b[j] = batch[__float_as_int(p[j].x)];
#pragma unroll
        for (int j = 0; j < 8; ++j) acc += (b[j] == lane) ? p[j].y : 0.0f;
    }
    for (; e < end; ++e) {
        float2 p = pack[e];
        acc += (batch[__float_as_int(p.x)] == lane) ? p.y : 0.0f;
    }
    Q[(wid << 6) + lane] = acc;
}

// ---------------- hops 2,3: Qout[n][g] = dinv^2*Qin[n][g] + sum nrm*Qin[src][g] ----------------
__global__ void k_hop_gather(const int* __restrict__ rowptr, const float2* __restrict__ pack,
                             const float* __restrict__ dinv, const float* __restrict__ Qin,
                             float* __restrict__ Qout) {
    int wid = (blockIdx.x * blockDim.x + threadIdx.x) >> 6;
    int lane = threadIdx.x & 63;
    if (wid >= NN) return;
    int beg = rowptr[wid], end = rowptr[wid + 1];
    float d = dinv[wid];
    float acc = d * d * Qin[(wid << 6) + lane];
    int e = beg;
    for (; e + 8 <= end; e += 8) {
        float2 p[8];
#pragma unroll
        for (int j = 0; j < 8; ++j) p[j] = pack[e + j];
        float q[8];
#pragma unroll
        for (int j = 0; j < 8; ++j) q[j] = Qin[(__float_as_int(p[j].x) << 6) + lane];
#pragma unroll
        for (int j = 0; j < 8; ++j) acc += p[j].y * q[j];
    }
    for (; e < end; ++e) {
        float2 p = pack[e];
        acc += p.y * Qin[(__float_as_int(p.x) << 6) + lane];
    }
    Qout[(wid << 6) + lane] = acc;
}

// ---------------- psum[g][f] = sum_n Q3[n][g] * x[n][f]  (tiled, 64 nodes/iter) ----------------
__global__ __launch_bounds__(256) void k_pool(const float* __restrict__ Q,
                                              const float* __restrict__ x,
                                              float* __restrict__ psum) {
    __shared__ float qs[PT * NG];   // 16 KB
    __shared__ float xs[PT * NF];   // 32 KB
    int t = threadIdx.x;
    int f4 = (t & 31) << 2;
    int g0 = (t >> 5) << 3;
    float4 acc[8];
#pragma unroll
    for (int i = 0; i < 8; ++i) acc[i] = make_float4(0.f, 0.f, 0.f, 0.f);

    const int NT = (NN + PT - 1) / PT;   // 1563
    for (int tile = blockIdx.x; tile < NT; tile += gridDim.x) {
        int n0 = tile * PT;
        int nt = min(PT, NN - n0);
        const float4* Q4 = (const float4*)(Q + (size_t)n0 * NG);
        const float4* X4 = (const float4*)(x + (size_t)n0 * NF);
        float4* qs4 = (float4*)qs;
        float4* xs4 = (float4*)xs;
        for (int i = t; i < nt * (NG / 4); i += 256) qs4[i] = Q4[i];
        for (int i = t; i < nt * (NF / 4); i += 256) xs4[i] = X4[i];
        __syncthreads();
        for (int n = 0; n < nt; ++n) {
            float4 xv = *(const float4*)&xs[n * NF + f4];
            float4 qa = *(const float4*)&qs[n * NG + g0];
            float4 qb = *(const float4*)&qs[n * NG + g0 + 4];
            float qv[8] = {qa.x, qa.y, qa.z, qa.w, qb.x, qb.y, qb.z, qb.w};
#pragma unroll
            for (int i = 0; i < 8; ++i) {
                acc[i].x += qv[i] * xv.x;
                acc[i].y += qv[i] * xv.y;
                acc[i].z += qv[i] * xv.z;
                acc[i].w += qv[i] * xv.w;
            }
        }
        __syncthreads();
    }
#pragma unroll
    for (int i = 0; i < 8; ++i) {
        atomicAdd(&psum[(g0 + i) * NF + f4 + 0], acc[i].x);
        atomicAdd(&psum[(g0 + i) * NF + f4 + 1], acc[i].y);
        atomicAdd(&psum[(g0 + i) * NF + f4 + 2], acc[i].z);
        atomicAdd(&psum[(g0 + i) * NF + f4 + 3], acc[i].w);
    }
}

// ---------------- final: fold both linears ----------------
__global__ void k_final(const float* __restrict__ psum, const float* __restrict__ cnt,
                        const float* __restrict__ Wc, const float* __restrict__ bc,
                        const float* __restrict__ Wl, const float* __restrict__ bl,
                        float* __restrict__ out) {
    __shared__ float M[NP * NH];
    __shared__ float bias[NP];
    int t = threadIdx.x;
    for (int idx = t; idx < NP * NH; idx += 256) {
        int p = idx >> 7, f = idx & 127;
        float s = 0.0f;
        for (int h = 0; h < NH; ++h) s += Wl[p * NH + h] * Wc[h * NF + f];
        M[idx] = s;
    }
    if (t < NP) {
        float s = bl[t];
        for (int h = 0; h < NH; ++h) s += Wl[t * NH + h] * bc[h];
        bias[t] = s;
    }
    __syncthreads();
    for (int idx = t; idx < NG * NP; idx += 256) {
        int g = idx >> 3, p = idx & 7;
        float inv = 1.0f / fmaxf(cnt[g], 1.0f);
        float s = 0.0f;
        for (int f = 0; f < NF; ++f) s += psum[g * NF + f] * M[p * NH + f];
        out[idx] = s * inv + bias[p];
    }
}

extern "C" void kernel_launch(void* const* d_in, const int* in_sizes, int n_in,
                              void* d_out, int out_size, void* d_ws, size_t ws_size,
                              hipStream_t stream) {
    const float* x     = (const float*)d_in[0];
    const int*   ei    = (const int*)d_in[1];
    const float* ea    = (const float*)d_in[2];
    const int*   batch = (const int*)d_in[3];
    const float* Wc    = (const float*)d_in[4];
    const float* bc    = (const float*)d_in[5];
    const float* Wl    = (const float*)d_in[6];
    const float* bl    = (const float*)d_in[7];
    const int* row = ei;           // edge_index[0]
    const int* col = ei + NE;      // edge_index[1]
    float* out = (float*)d_out;

    // ---- workspace (~77.7 MB) ----
    // H aliases Qa; Hd aliases Qb; scan scratch aliases pack (all dead before
    // their alias partner is first written).
    float* ws     = (float*)d_ws;
    float*  dinv   = ws;                          // NN
    int*    rowptr = (int*)(dinv + NN);           // NN+2
    float*  cnt    = (float*)(rowptr + NN + 2);   // NG
    float*  psum   = cnt + NG;                    // NG*NH
    float2* pack   = (float2*)(psum + NG * NH);   // NE float2
    float*  Qb     = (float*)(pack + NE);         // NN*64
    float*  Qa     = Qb + (size_t)NN * NG;        // NN*64
    unsigned* H  = (unsigned*)Qa;                 // NW*NN
    float*    Hd = Qb;                            // NW*NN
    int* rcnt = (int*)pack;                       // NN
    int* px   = rcnt + SCAN_NBLK * SCAN_B;        // SCAN_NBLK*SCAN_B
    int* bsum = px + SCAN_NBLK * SCAN_B;          // SCAN_NBLK
    int* bofs = bsum + SCAN_NBLK;                 // SCAN_NBLK

    const int B = 256;
    int gN  = (NN + B - 1) / B;                          // 391
    int gCW = NC * NW;                                   // 448
    int gW  = (int)(((long long)NN * 64 + B - 1) / B);   // 25000

    k_init<<<(NG * NH + B - 1) / B, B, 0, stream>>>(cnt, psum);
    k_hist<<<gCW, B, 0, stream>>>(row, H);
    k_deg_hist<<<gCW, B, 0, stream>>>(col, ea, Hd);
    k_cnt<<<gN, B, 0, stream>>>(batch, cnt);
    k_reduce<<<gN, B, 0, stream>>>(H, Hd, rcnt, dinv);

    k_scan1<<<SCAN_NBLK, SCAN_B, 0, stream>>>(rcnt, px, bsum);
    k_scan2<<<1, 64, 0, stream>>>(bsum, bofs);
    k_scan3<<<(NN + 1 + SCAN_B - 1) / SCAN_B, SCAN_B, 0, stream>>>(px, bofs, rowptr);
    k_base<<<gN, B, 0, stream>>>(rowptr, H);
    k_sort<<<gCW, B, 0, stream>>>(row, col, ea, H, dinv, pack);

    k_q1_gather<<<gW, B, 0, stream>>>(rowptr, pack, batch, dinv, Qa);
    k_hop_gather<<<gW, B, 0, stream>>>(rowptr, pack, dinv, Qa, Qb);
    k_hop_gather<<<gW, B, 0, stream>>>(rowptr, pack, dinv, Qb, Qa);

    k_pool<<<512, B, 0, stream>>>(Qa, x, psum);
    k_final<<<1, B, 0, stream>>>(psum, cnt, Wc, bc, Wl, bl, out);
}

// Round 7
// 716.661 us; speedup vs baseline: 1.6122x; 1.1365x over previous
//
#include <hip/hip_runtime.h>

#define NN 100000      // N_NODES
#define NE 3200000     // N_EDGES
#define NF 128         // N_F
#define NH 128         // HIDDEN
#define NP 8           // N_PRED
#define NG 64          // N_GRAPHS

#define CS 16000       // bins per chunk (64 KB LDS as u32/f32)
#define NC 7           // ceil(100000/16000)
#define NW 64          // edge slices
#define ES (NE / NW)   // 50000 edges per slice (divisible by 8)

#define PT 64          // k_pool node tile

#define SCAN_B 1024
#define SCAN_NBLK 98   // ceil(100000/1024)

// f32 -> bf16 (RNE), bf16 -> f32 (shift)
__device__ __forceinline__ unsigned short f2bf(float f) {
    unsigned u = __float_as_uint(f);
    return (unsigned short)((u + 0x7fffu + ((u >> 16) & 1u)) >> 16);
}
__device__ __forceinline__ float bf2f(unsigned short b) {
    return __uint_as_float((unsigned)b << 16);
}

// ---------------- init: cnt, psum ----------------
__global__ void k_init(float* __restrict__ cnt, float* __restrict__ psum) {
    int i = blockIdx.x * blockDim.x + threadIdx.x;
    if (i < NG) cnt[i] = 0.0f;
    if (i < NG * NH) psum[i] = 0.0f;
}

// ---------------- row histogram: H[w][r] via LDS, 8-edge vector loads ----------------
__global__ __launch_bounds__(256) void k_hist(const int* __restrict__ row,
                                              unsigned* __restrict__ H) {
    __shared__ unsigned hist[CS];
    int w = blockIdx.x % NW, c = blockIdx.x / NW;
    int rbase = c * CS;
    int nb = (rbase + CS <= NN) ? CS : (NN - rbase);
    for (int i = threadIdx.x; i < nb; i += 256) hist[i] = 0u;
    __syncthreads();
    const int4* r4 = (const int4*)(row + (size_t)w * ES);
    for (int i = threadIdx.x; i < ES / 8; i += 256) {
        int4 a = r4[2 * i], b = r4[2 * i + 1];
        int rs[8] = {a.x, a.y, a.z, a.w, b.x, b.y, b.z, b.w};
#pragma unroll
        for (int j = 0; j < 8; ++j) {
            unsigned rr = (unsigned)(rs[j] - rbase);
            if (rr < (unsigned)nb) atomicAdd(&hist[rr], 1u);
        }
    }
    __syncthreads();
    for (int i = threadIdx.x; i < nb; i += 256) H[(size_t)w * NN + rbase + i] = hist[i];
}

// ---------------- weighted col histogram: Hd[w][c] via LDS, vector loads ----------------
__global__ __launch_bounds__(256) void k_deg_hist(const int* __restrict__ col,
                                                  const float* __restrict__ wt,
                                                  float* __restrict__ Hd) {
    __shared__ float dh[CS];
    int w = blockIdx.x % NW, c = blockIdx.x / NW;
    int rbase = c * CS;
    int nb = (rbase + CS <= NN) ? CS : (NN - rbase);
    for (int i = threadIdx.x; i < nb; i += 256) dh[i] = 0.0f;
    __syncthreads();
    const int4*   c4 = (const int4*)(col + (size_t)w * ES);
    const float4* w4 = (const float4*)(wt + (size_t)w * ES);
    for (int i = threadIdx.x; i < ES / 8; i += 256) {
        int4 a = c4[2 * i], b = c4[2 * i + 1];
        float4 wa = w4[2 * i], wb = w4[2 * i + 1];
        int cc[8] = {a.x, a.y, a.z, a.w, b.x, b.y, b.z, b.w};
        float ww[8] = {wa.x, wa.y, wa.z, wa.w, wb.x, wb.y, wb.z, wb.w};
#pragma unroll
        for (int j = 0; j < 8; ++j) {
            unsigned rr = (unsigned)(cc[j] - rbase);
            if (rr < (unsigned)nb) atomicAdd(&dh[rr], ww[j]);
        }
    }
    __syncthreads();
    for (int i = threadIdx.x; i < nb; i += 256) Hd[(size_t)w * NN + rbase + i] = dh[i];
}

// ---------------- per-graph node counts ----------------
__global__ void k_cnt(const int* __restrict__ batch, float* __restrict__ cnt) {
    __shared__ float c[NG];
    int t = threadIdx.x;
    if (t < NG) c[t] = 0.0f;
    __syncthreads();
    int i = blockIdx.x * blockDim.x + t;
    if (i < NN) atomicAdd(&c[batch[i]], 1.0f);
    __syncthreads();
    if (t < NG && c[t] != 0.0f) atomicAdd(&cnt[t], c[t]);
}

// ---------------- reduce slices: rcnt[r] = sum_w H, dinv[r] = rsqrt(1 + sum_w Hd) ----------------
__global__ void k_reduce(const unsigned* __restrict__ H, const float* __restrict__ Hd,
                         int* __restrict__ rcnt, float* __restrict__ dinv) {
    int r = blockIdx.x * blockDim.x + threadIdx.x;
    if (r >= NN) return;
    unsigned s = 0;
    float d = 1.0f;   // self-loop weight
#pragma unroll
    for (int w = 0; w < NW; ++w) {
        s += H[(size_t)w * NN + r];
        d += Hd[(size_t)w * NN + r];
    }
    rcnt[r] = (int)s;
    dinv[r] = rsqrtf(d);
}

// ---------------- scan pass 1 ----------------
__global__ __launch_bounds__(SCAN_B) void k_scan1(const int* __restrict__ rcnt,
                                                  int* __restrict__ px,
                                                  int* __restrict__ bsum) {
    __shared__ int s[SCAN_B];
    int t = threadIdx.x;
    int i = blockIdx.x * SCAN_B + t;
    int v = (i < NN) ? rcnt[i] : 0;
    s[t] = v;
    __syncthreads();
    for (int off = 1; off < SCAN_B; off <<= 1) {
        int x = (t >= off) ? s[t - off] : 0;
        __syncthreads();
        s[t] += x;
        __syncthreads();
    }
    px[i] = s[t] - v;
    if (t == SCAN_B - 1) bsum[blockIdx.x] = s[t];
}

// ---------------- scan pass 2 ----------------
__global__ void k_scan2(const int* __restrict__ bsum, int* __restrict__ bofs) {
    if (threadIdx.x == 0) {
        int acc = 0;
        for (int b = 0; b < SCAN_NBLK; ++b) { bofs[b] = acc; acc += bsum[b]; }
    }
}

// ---------------- scan pass 3: rowptr ----------------
__global__ void k_scan3(const int* __restrict__ px, const int* __restrict__ bofs,
                        int* __restrict__ rowptr) {
    int i = blockIdx.x * blockDim.x + threadIdx.x;
    if (i > NN) return;
    rowptr[i] = px[i] + bofs[i >> 10];
}

// ---------------- H -> per-(row,slice) base offsets (in place) ----------------
__global__ void k_base(const int* __restrict__ rowptr, unsigned* __restrict__ H) {
    int r = blockIdx.x * blockDim.x + threadIdx.x;
    if (r >= NN) return;
    unsigned acc = (unsigned)rowptr[r];
#pragma unroll
    for (int w = 0; w < NW; ++w) {
        unsigned v = H[(size_t)w * NN + r];
        H[(size_t)w * NN + r] = acc;
        acc += v;
    }
}

// ---------------- stable counting-sort scatter, vector loads ----------------
__global__ __launch_bounds__(256) void k_sort(const int* __restrict__ row,
                                              const int* __restrict__ col,
                                              const float* __restrict__ wt,
                                              const unsigned* __restrict__ B,
                                              const float* __restrict__ dinv,
                                              float2* __restrict__ pack) {
    __shared__ unsigned basel[CS];
    int w = blockIdx.x % NW, c = blockIdx.x / NW;
    int rbase = c * CS;
    int nb = (rbase + CS <= NN) ? CS : (NN - rbase);
    for (int i = threadIdx.x; i < nb; i += 256)
        basel[i] = B[(size_t)w * NN + rbase + i];
    __syncthreads();
    const int4*   r4 = (const int4*)(row + (size_t)w * ES);
    const int4*   c4 = (const int4*)(col + (size_t)w * ES);
    const float4* w4 = (const float4*)(wt + (size_t)w * ES);
    for (int i = threadIdx.x; i < ES / 8; i += 256) {
        int4 ra = r4[2 * i], rb = r4[2 * i + 1];
        int4 ca = c4[2 * i], cb = c4[2 * i + 1];
        float4 wa = w4[2 * i], wb = w4[2 * i + 1];
        int rs[8] = {ra.x, ra.y, ra.z, ra.w, rb.x, rb.y, rb.z, rb.w};
        int cs[8] = {ca.x, ca.y, ca.z, ca.w, cb.x, cb.y, cb.z, cb.w};
        float ww[8] = {wa.x, wa.y, wa.z, wa.w, wb.x, wb.y, wb.z, wb.w};
#pragma unroll
        for (int j = 0; j < 8; ++j) {
            unsigned rr = (unsigned)(rs[j] - rbase);
            if (rr < (unsigned)nb) {
                unsigned pos = atomicAdd(&basel[rr], 1u);
                pack[pos] = make_float2(__int_as_float(cs[j]),
                                        dinv[rs[j]] * ww[j] * dinv[cs[j]]);
            }
        }
    }
}

// ---------------- hop 1 (bf16 out): Qa[n][g] = dinv^2*(batch[n]==g) + sum nrm*(batch[src]==g) ----------------
__global__ void k_q1_gather(const int* __restrict__ rowptr, const float2* __restrict__ pack,
                            const int* __restrict__ batch, const float* __restrict__ dinv,
                            unsigned short* __restrict__ Q) {
    int wid = (blockIdx.x * blockDim.x + threadIdx.x) >> 6;
    int lane = threadIdx.x & 63;
    if (wid >= NN) return;
    int beg = rowptr[wid], end = rowptr[wid + 1];
    float d = dinv[wid];
    float acc = (batch[wid] == lane) ? d * d : 0.0f;
    int e = beg;
    for (; e + 8 <= end; e += 8) {
        float2 p[8];
#pragma unroll
        for (int j = 0; j < 8; ++j) p[j] = pack[e + j];
        int b[8];
#pragma unroll
        for (int j = 0; j < 8; ++j) b[j] = batch[__float_as_int(p[j].x)];
#pragma unroll
        for (int j = 0; j < 8; ++j) acc += (b[j] == lane) ? p[j].y : 0.0f;
    }
    for (; e < end; ++e) {
        float2 p = pack[e];
        acc += (batch[__float_as_int(p.x)] == lane) ? p.y : 0.0f;
    }
    Q[(wid << 6) + lane] = f2bf(acc);
}

// ---------------- hops 2,3 (bf16 in/out): Qout[n][g] = dinv^2*Qin[n][g] + sum nrm*Qin[src][g] ----------------
__global__ void k_hop_gather(const int* __restrict__ rowptr, const float2* __restrict__ pack,
                             const float* __restrict__ dinv,
                             const unsigned short* __restrict__ Qin,
                             unsigned short* __restrict__ Qout) {
    int wid = (blockIdx.x * blockDim.x + threadIdx.x) >> 6;
    int lane = threadIdx.x & 63;
    if (wid >= NN) return;
    int beg = rowptr[wid], end = rowptr[wid + 1];
    float d = dinv[wid];
    float acc = d * d * bf2f(Qin[(wid << 6) + lane]);
    int e = beg;
    for (; e + 8 <= end; e += 8) {
        float2 p[8];
#pragma unroll
        for (int j = 0; j < 8; ++j) p[j] = pack[e + j];
        unsigned short q[8];
#pragma unroll
        for (int j = 0; j < 8; ++j) q[j] = Qin[(__float_as_int(p[j].x) << 6) + lane];
#pragma unroll
        for (int j = 0; j < 8; ++j) acc += p[j].y * bf2f(q[j]);
    }
    for (; e < end; ++e) {
        float2 p = pack[e];
        acc += p.y * bf2f(Qin[(__float_as_int(p.x) << 6) + lane]);
    }
    Qout[(wid << 6) + lane] = f2bf(acc);
}

// ---------------- psum[g][f] = sum_n Q3[n][g] * x[n][f]  (tiled, bf16 Q) ----------------
__global__ __launch_bounds__(256) void k_pool(const unsigned short* __restrict__ Q,
                                              const float* __restrict__ x,
                                              float* __restrict__ psum) {
    __shared__ float qs[PT * NG];   // 16 KB (converted to f32 at stage)
    __shared__ float xs[PT * NF];   // 32 KB
    int t = threadIdx.x;
    int f4 = (t & 31) << 2;
    int g0 = (t >> 5) << 3;
    float4 acc[8];
#pragma unroll
    for (int i = 0; i < 8; ++i) acc[i] = make_float4(0.f, 0.f, 0.f, 0.f);

    const int NT = (NN + PT - 1) / PT;   // 1563
    for (int tile = blockIdx.x; tile < NT; tile += gridDim.x) {
        int n0 = tile * PT;
        int nt = min(PT, NN - n0);
        const unsigned* Q2 = (const unsigned*)(Q + (size_t)n0 * NG);  // 2 bf16 per u32
        const float4* X4 = (const float4*)(x + (size_t)n0 * NF);
        float4* xs4 = (float4*)xs;
        for (int i = t; i < nt * (NG / 2); i += 256) {
            unsigned v = Q2[i];
            qs[2 * i]     = __uint_as_float(v << 16);
            qs[2 * i + 1] = __uint_as_float(v & 0xffff0000u);
        }
        for (int i = t; i < nt * (NF / 4); i += 256) xs4[i] = X4[i];
        __syncthreads();
        for (int n = 0; n < nt; ++n) {
            float4 xv = *(const float4*)&xs[n * NF + f4];
            float4 qa = *(const float4*)&qs[n * NG + g0];
            float4 qb = *(const float4*)&qs[n * NG + g0 + 4];
            float qv[8] = {qa.x, qa.y, qa.z, qa.w, qb.x, qb.y, qb.z, qb.w};
#pragma unroll
            for (int i = 0; i < 8; ++i) {
                acc[i].x += qv[i] * xv.x;
                acc[i].y += qv[i] * xv.y;
                acc[i].z += qv[i] * xv.z;
                acc[i].w += qv[i] * xv.w;
            }
        }
        __syncthreads();
    }
#pragma unroll
    for (int i = 0; i < 8; ++i) {
        atomicAdd(&psum[(g0 + i) * NF + f4 + 0], acc[i].x);
        atomicAdd(&psum[(g0 + i) * NF + f4 + 1], acc[i].y);
        atomicAdd(&psum[(g0 + i) * NF + f4 + 2], acc[i].z);
        atomicAdd(&psum[(g0 + i) * NF + f4 + 3], acc[i].w);
    }
}

// ---------------- final: fold both linears ----------------
__global__ void k_final(const float* __restrict__ psum, const float* __restrict__ cnt,
                        const float* __restrict__ Wc, const float* __restrict__ bc,
                        const float* __restrict__ Wl, const float* __restrict__ bl,
                        float* __restrict__ out) {
    __shared__ float M[NP * NH];
    __shared__ float bias[NP];
    int t = threadIdx.x;
    for (int idx = t; idx < NP * NH; idx += 256) {
        int p = idx >> 7, f = idx & 127;
        float s = 0.0f;
        for (int h = 0; h < NH; ++h) s += Wl[p * NH + h] * Wc[h * NF + f];
        M[idx] = s;
    }
    if (t < NP) {
        float s = bl[t];
        for (int h = 0; h < NH; ++h) s += Wl[t * NH + h] * bc[h];
        bias[t] = s;
    }
    __syncthreads();
    for (int idx = t; idx < NG * NP; idx += 256) {
        int g = idx >> 3, p = idx & 7;
        float inv = 1.0f / fmaxf(cnt[g], 1.0f);
        float s = 0.0f;
        for (int f = 0; f < NF; ++f) s += psum[g * NF + f] * M[p * NH + f];
        out[idx] = s * inv + bias[p];
    }
}

extern "C" void kernel_launch(void* const* d_in, const int* in_sizes, int n_in,
                              void* d_out, int out_size, void* d_ws, size_t ws_size,
                              hipStream_t stream) {
    const float* x     = (const float*)d_in[0];
    const int*   ei    = (const int*)d_in[1];
    const float* ea    = (const float*)d_in[2];
    const int*   batch = (const int*)d_in[3];
    const float* Wc    = (const float*)d_in[4];
    const float* bc    = (const float*)d_in[5];
    const float* Wl    = (const float*)d_in[6];
    const float* bl    = (const float*)d_in[7];
    const int* row = ei;           // edge_index[0]
    const int* col = ei + NE;      // edge_index[1]
    float* out = (float*)d_out;

    // ---- workspace (~77.7 MB, unchanged footprint) ----
    // Scan scratch aliases pack (dead before k_sort writes pack).
    // Qa+Qb (bf16, 12.8 MB each) exactly fill the H block (dead after k_sort).
    // Hd dies after k_reduce.
    float* ws     = (float*)d_ws;
    float*  dinv   = ws;                          // NN
    int*    rowptr = (int*)(dinv + NN);           // NN+2
    float*  cnt    = (float*)(rowptr + NN + 2);   // NG
    float*  psum   = cnt + NG;                    // NG*NH
    float2* pack   = (float2*)(psum + NG * NH);   // NE float2
    unsigned* H    = (unsigned*)(pack + NE);      // NW*NN (25.6 MB)
    float*    Hd   = (float*)(H + (size_t)NW * NN); // NW*NN (25.6 MB)
    unsigned short* Qa = (unsigned short*)H;              // NN*64 bf16
    unsigned short* Qb = Qa + (size_t)NN * NG;            // NN*64 bf16
    int* rcnt = (int*)pack;                       // scan scratch (aliases pack)
    int* px   = rcnt + SCAN_NBLK * SCAN_B;
    int* bsum = px + SCAN_NBLK * SCAN_B;
    int* bofs = bsum + SCAN_NBLK;

    const int B = 256;
    int gN  = (NN + B - 1) / B;                          // 391
    int gCW = NC * NW;                                   // 448
    int gW  = (int)(((long long)NN * 64 + B - 1) / B);   // 25000

    k_init<<<(NG * NH + B - 1) / B, B, 0, stream>>>(cnt, psum);
    k_hist<<<gCW, B, 0, stream>>>(row, H);
    k_deg_hist<<<gCW, B, 0, stream>>>(col, ea, Hd);
    k_cnt<<<gN, B, 0, stream>>>(batch, cnt);
    k_reduce<<<gN, B, 0, stream>>>(H, Hd, rcnt, dinv);

    k_scan1<<<SCAN_NBLK, SCAN_B, 0, stream>>>(rcnt, px, bsum);
    k_scan2<<<1, 64, 0, stream>>>(bsum, bofs);
    k_scan3<<<(NN + 1 + SCAN_B - 1) / SCAN_B, SCAN_B, 0, stream>>>(px, bofs, rowptr);
    k_base<<<gN, B, 0, stream>>>(rowptr, H);
    k_sort<<<gCW, B, 0, stream>>>(row, col, ea, H, dinv, pack);

    // NOTE: k_q1_gather overwrites the H region (as Qa) — H is dead after k_sort.
    k_q1_gather<<<gW, B, 0, stream>>>(rowptr, pack, batch, dinv, Qa);
    k_hop_gather<<<gW, B, 0, stream>>>(rowptr, pack, dinv, Qa, Qb);
    k_hop_gather<<<gW, B, 0, stream>>>(rowptr, pack, dinv, Qb, Qa);

    k_pool<<<512, B, 0, stream>>>(Qa, x, psum);
    k_final<<<1, B, 0, stream>>>(psum, cnt, Wc, bc, Wl, bl, out);
}

// Round 8
// 681.429 us; speedup vs baseline: 1.6956x; 1.0517x over previous
//
#include <hip/hip_runtime.h>

#define NN 100000      // N_NODES
#define NE 3200000     // N_EDGES
#define NF 128         // N_F
#define NH 128         // HIDDEN
#define NP 8           // N_PRED
#define NG 64          // N_GRAPHS

#define CS 16000       // bins per chunk (64 KB LDS as u32/f32)
#define NC 7           // ceil(100000/16000)
#define NW 64          // edge slices
#define ES (NE / NW)   // 50000 edges per slice (divisible by 8)

#define PT 64          // k_pool node tile
#define GP 1024        // k_pool grid (4 blocks/CU at 40 KB LDS)

#define SCAN_B 1024
#define SCAN_NBLK 98   // ceil(100000/1024)

// f32 -> bf16 (RNE), bf16 -> f32 (shift)
__device__ __forceinline__ unsigned short f2bf(float f) {
    unsigned u = __float_as_uint(f);
    return (unsigned short)((u + 0x7fffu + ((u >> 16) & 1u)) >> 16);
}
__device__ __forceinline__ float bf2f(unsigned short b) {
    return __uint_as_float((unsigned)b << 16);
}

// ---------------- init: cnt, psum ----------------
__global__ void k_init(float* __restrict__ cnt, float* __restrict__ psum) {
    int i = blockIdx.x * blockDim.x + threadIdx.x;
    if (i < NG) cnt[i] = 0.0f;
    if (i < NG * NH) psum[i] = 0.0f;
}

// ---------------- row histogram: H[w][r] via LDS, 8-edge vector loads ----------------
__global__ __launch_bounds__(256) void k_hist(const int* __restrict__ row,
                                              unsigned* __restrict__ H) {
    __shared__ unsigned hist[CS];
    int w = blockIdx.x % NW, c = blockIdx.x / NW;
    int rbase = c * CS;
    int nb = (rbase + CS <= NN) ? CS : (NN - rbase);
    for (int i = threadIdx.x; i < nb; i += 256) hist[i] = 0u;
    __syncthreads();
    const int4* r4 = (const int4*)(row + (size_t)w * ES);
    for (int i = threadIdx.x; i < ES / 8; i += 256) {
        int4 a = r4[2 * i], b = r4[2 * i + 1];
        int rs[8] = {a.x, a.y, a.z, a.w, b.x, b.y, b.z, b.w};
#pragma unroll
        for (int j = 0; j < 8; ++j) {
            unsigned rr = (unsigned)(rs[j] - rbase);
            if (rr < (unsigned)nb) atomicAdd(&hist[rr], 1u);
        }
    }
    __syncthreads();
    for (int i = threadIdx.x; i < nb; i += 256) H[(size_t)w * NN + rbase + i] = hist[i];
}

// ---------------- weighted col histogram: Hd[w][c] via LDS, vector loads ----------------
__global__ __launch_bounds__(256) void k_deg_hist(const int* __restrict__ col,
                                                  const float* __restrict__ wt,
                                                  float* __restrict__ Hd) {
    __shared__ float dh[CS];
    int w = blockIdx.x % NW, c = blockIdx.x / NW;
    int rbase = c * CS;
    int nb = (rbase + CS <= NN) ? CS : (NN - rbase);
    for (int i = threadIdx.x; i < nb; i += 256) dh[i] = 0.0f;
    __syncthreads();
    const int4*   c4 = (const int4*)(col + (size_t)w * ES);
    const float4* w4 = (const float4*)(wt + (size_t)w * ES);
    for (int i = threadIdx.x; i < ES / 8; i += 256) {
        int4 a = c4[2 * i], b = c4[2 * i + 1];
        float4 wa = w4[2 * i], wb = w4[2 * i + 1];
        int cc[8] = {a.x, a.y, a.z, a.w, b.x, b.y, b.z, b.w};
        float ww[8] = {wa.x, wa.y, wa.z, wa.w, wb.x, wb.y, wb.z, wb.w};
#pragma unroll
        for (int j = 0; j < 8; ++j) {
            unsigned rr = (unsigned)(cc[j] - rbase);
            if (rr < (unsigned)nb) atomicAdd(&dh[rr], ww[j]);
        }
    }
    __syncthreads();
    for (int i = threadIdx.x; i < nb; i += 256) Hd[(size_t)w * NN + rbase + i] = dh[i];
}

// ---------------- per-graph node counts ----------------
__global__ void k_cnt(const int* __restrict__ batch, float* __restrict__ cnt) {
    __shared__ float c[NG];
    int t = threadIdx.x;
    if (t < NG) c[t] = 0.0f;
    __syncthreads();
    int i = blockIdx.x * blockDim.x + t;
    if (i < NN) atomicAdd(&c[batch[i]], 1.0f);
    __syncthreads();
    if (t < NG && c[t] != 0.0f) atomicAdd(&cnt[t], c[t]);
}

// ---------------- reduce slices: rcnt[r] = sum_w H, dinv[r] = rsqrt(1 + sum_w Hd) ----------------
__global__ void k_reduce(const unsigned* __restrict__ H, const float* __restrict__ Hd,
                         int* __restrict__ rcnt, float* __restrict__ dinv) {
    int r = blockIdx.x * blockDim.x + threadIdx.x;
    if (r >= NN) return;
    unsigned s = 0;
    float d = 1.0f;   // self-loop weight
#pragma unroll
    for (int w = 0; w < NW; ++w) {
        s += H[(size_t)w * NN + r];
        d += Hd[(size_t)w * NN + r];
    }
    rcnt[r] = (int)s;
    dinv[r] = rsqrtf(d);
}

// ---------------- scan pass 1 ----------------
__global__ __launch_bounds__(SCAN_B) void k_scan1(const int* __restrict__ rcnt,
                                                  int* __restrict__ px,
                                                  int* __restrict__ bsum) {
    __shared__ int s[SCAN_B];
    int t = threadIdx.x;
    int i = blockIdx.x * SCAN_B + t;
    int v = (i < NN) ? rcnt[i] : 0;
    s[t] = v;
    __syncthreads();
    for (int off = 1; off < SCAN_B; off <<= 1) {
        int x = (t >= off) ? s[t - off] : 0;
        __syncthreads();
        s[t] += x;
        __syncthreads();
    }
    px[i] = s[t] - v;
    if (t == SCAN_B - 1) bsum[blockIdx.x] = s[t];
}

// ---------------- scan pass 2 ----------------
__global__ void k_scan2(const int* __restrict__ bsum, int* __restrict__ bofs) {
    if (threadIdx.x == 0) {
        int acc = 0;
        for (int b = 0; b < SCAN_NBLK; ++b) { bofs[b] = acc; acc += bsum[b]; }
    }
}

// ---------------- scan pass 3: rowptr ----------------
__global__ void k_scan3(const int* __restrict__ px, const int* __restrict__ bofs,
                        int* __restrict__ rowptr) {
    int i = blockIdx.x * blockDim.x + threadIdx.x;
    if (i > NN) return;
    rowptr[i] = px[i] + bofs[i >> 10];
}

// ---------------- H -> per-(row,slice) base offsets (in place) ----------------
__global__ void k_base(const int* __restrict__ rowptr, unsigned* __restrict__ H) {
    int r = blockIdx.x * blockDim.x + threadIdx.x;
    if (r >= NN) return;
    unsigned acc = (unsigned)rowptr[r];
#pragma unroll
    for (int w = 0; w < NW; ++w) {
        unsigned v = H[(size_t)w * NN + r];
        H[(size_t)w * NN + r] = acc;
        acc += v;
    }
}

// ---------------- stable counting-sort scatter, vector loads ----------------
__global__ __launch_bounds__(256) void k_sort(const int* __restrict__ row,
                                              const int* __restrict__ col,
                                              const float* __restrict__ wt,
                                              const unsigned* __restrict__ B,
                                              const float* __restrict__ dinv,
                                              float2* __restrict__ pack) {
    __shared__ unsigned basel[CS];
    int w = blockIdx.x % NW, c = blockIdx.x / NW;
    int rbase = c * CS;
    int nb = (rbase + CS <= NN) ? CS : (NN - rbase);
    for (int i = threadIdx.x; i < nb; i += 256)
        basel[i] = B[(size_t)w * NN + rbase + i];
    __syncthreads();
    const int4*   r4 = (const int4*)(row + (size_t)w * ES);
    const int4*   c4 = (const int4*)(col + (size_t)w * ES);
    const float4* w4 = (const float4*)(wt + (size_t)w * ES);
    for (int i = threadIdx.x; i < ES / 8; i += 256) {
        int4 ra = r4[2 * i], rb = r4[2 * i + 1];
        int4 ca = c4[2 * i], cb = c4[2 * i + 1];
        float4 wa = w4[2 * i], wb = w4[2 * i + 1];
        int rs[8] = {ra.x, ra.y, ra.z, ra.w, rb.x, rb.y, rb.z, rb.w};
        int cs[8] = {ca.x, ca.y, ca.z, ca.w, cb.x, cb.y, cb.z, cb.w};
        float ww[8] = {wa.x, wa.y, wa.z, wa.w, wb.x, wb.y, wb.z, wb.w};
#pragma unroll
        for (int j = 0; j < 8; ++j) {
            unsigned rr = (unsigned)(rs[j] - rbase);
            if (rr < (unsigned)nb) {
                unsigned pos = atomicAdd(&basel[rr], 1u);
                pack[pos] = make_float2(__int_as_float(cs[j]),
                                        dinv[rs[j]] * ww[j] * dinv[cs[j]]);
            }
        }
    }
}

// ---------------- hop 1 (bf16 out): Qa[n][g] = dinv^2*(batch[n]==g) + sum nrm*(batch[src]==g) ----------------
__global__ void k_q1_gather(const int* __restrict__ rowptr, const float2* __restrict__ pack,
                            const int* __restrict__ batch, const float* __restrict__ dinv,
                            unsigned short* __restrict__ Q) {
    int wid = (blockIdx.x * blockDim.x + threadIdx.x) >> 6;
    int lane = threadIdx.x & 63;
    if (wid >= NN) return;
    int beg = rowptr[wid], end = rowptr[wid + 1];
    float d = dinv[wid];
    float acc = (batch[wid] == lane) ? d * d : 0.0f;
    int e = beg;
    for (; e + 8 <= end; e += 8) {
        float2 p[8];
#pragma unroll
        for (int j = 0; j < 8; ++j) p[j] = pack[e + j];
        int b[8];
#pragma unroll
        for (int j = 0; j < 8; ++j) b[j] = batch[__float_as_int(p[j].x)];
#pragma unroll
        for (int j = 0; j < 8; ++j) acc += (b[j] == lane) ? p[j].y : 0.0f;
    }
    for (; e < end; ++e) {
        float2 p = pack[e];
        acc += (batch[__float_as_int(p.x)] == lane) ? p.y : 0.0f;
    }
    Q[(wid << 6) + lane] = f2bf(acc);
}

// ---------------- hops 2,3 (bf16 in/out): Qout[n][g] = dinv^2*Qin[n][g] + sum nrm*Qin[src][g] ----------------
__global__ void k_hop_gather(const int* __restrict__ rowptr, const float2* __restrict__ pack,
                             const float* __restrict__ dinv,
                             const unsigned short* __restrict__ Qin,
                             unsigned short* __restrict__ Qout) {
    int wid = (blockIdx.x * blockDim.x + threadIdx.x) >> 6;
    int lane = threadIdx.x & 63;
    if (wid >= NN) return;
    int beg = rowptr[wid], end = rowptr[wid + 1];
    float d = dinv[wid];
    float acc = d * d * bf2f(Qin[(wid << 6) + lane]);
    int e = beg;
    for (; e + 8 <= end; e += 8) {
        float2 p[8];
#pragma unroll
        for (int j = 0; j < 8; ++j) p[j] = pack[e + j];
        unsigned short q[8];
#pragma unroll
        for (int j = 0; j < 8; ++j) q[j] = Qin[(__float_as_int(p[j].x) << 6) + lane];
#pragma unroll
        for (int j = 0; j < 8; ++j) acc += p[j].y * bf2f(q[j]);
    }
    for (; e < end; ++e) {
        float2 p = pack[e];
        acc += p.y * bf2f(Qin[(__float_as_int(p.x) << 6) + lane]);
    }
    Qout[(wid << 6) + lane] = f2bf(acc);
}

// ---------------- pool: per-block partial[g][f] = sum_n Q3[n][g]*x[n][f] ----------------
// 40 KB LDS -> 4 blocks/CU; NO trailing atomics (plain float4 partial stores).
__global__ __launch_bounds__(256) void k_pool(const unsigned short* __restrict__ Q,
                                              const float* __restrict__ x,
                                              float* __restrict__ partial) {
    __shared__ unsigned short qsh[PT * NG];   // 8 KB (bf16)
    __shared__ float xs[PT * NF];             // 32 KB
    int t = threadIdx.x;
    int f4 = (t & 31) << 2;
    int g0 = (t >> 5) << 3;
    float4 acc[8];
#pragma unroll
    for (int i = 0; i < 8; ++i) acc[i] = make_float4(0.f, 0.f, 0.f, 0.f);

    const int NT = (NN + PT - 1) / PT;   // 1563
    for (int tile = blockIdx.x; tile < NT; tile += GP) {
        int n0 = tile * PT;
        int nt = min(PT, NN - n0);
        const uint4*  Q4 = (const uint4*)(Q + (size_t)n0 * NG);
        const float4* X4 = (const float4*)(x + (size_t)n0 * NF);
        uint4*  qs4 = (uint4*)qsh;
        float4* xs4 = (float4*)xs;
        for (int i = t; i < nt * (NG / 8); i += 256) qs4[i] = Q4[i];
        for (int i = t; i < nt * (NF / 4); i += 256) xs4[i] = X4[i];
        __syncthreads();
        for (int n = 0; n < nt; ++n) {
            float4 xv = *(const float4*)&xs[n * NF + f4];
            uint4 qu = *(const uint4*)&qsh[n * NG + g0];
            float qv[8];
            qv[0] = __uint_as_float(qu.x << 16);
            qv[1] = __uint_as_float(qu.x & 0xffff0000u);
            qv[2] = __uint_as_float(qu.y << 16);
            qv[3] = __uint_as_float(qu.y & 0xffff0000u);
            qv[4] = __uint_as_float(qu.z << 16);
            qv[5] = __uint_as_float(qu.z & 0xffff0000u);
            qv[6] = __uint_as_float(qu.w << 16);
            qv[7] = __uint_as_float(qu.w & 0xffff0000u);
#pragma unroll
            for (int i = 0; i < 8; ++i) {
                acc[i].x += qv[i] * xv.x;
                acc[i].y += qv[i] * xv.y;
                acc[i].z += qv[i] * xv.z;
                acc[i].w += qv[i] * xv.w;
            }
        }
        __syncthreads();
    }
    float* pb = partial + (size_t)blockIdx.x * (NG * NF);
#pragma unroll
    for (int i = 0; i < 8; ++i)
        *(float4*)&pb[(g0 + i) * NF + f4] = acc[i];
}

// ---------------- reduce GP partial slabs -> psum (8-way split-K) ----------------
__global__ void k_red(const float* __restrict__ partial, float* __restrict__ psum) {
    int gid = blockIdx.x * blockDim.x + threadIdx.x;   // 65536 threads
    int idx = gid & (NG * NF - 1);
    int j = gid >> 13;                                 // 0..7
    float acc = 0.0f;
    for (int b = j; b < GP; b += 8)
        acc += partial[(size_t)b * (NG * NF) + idx];
    atomicAdd(&psum[idx], acc);
}

// ---------------- final: fold both linears ----------------
__global__ void k_final(const float* __restrict__ psum, const float* __restrict__ cnt,
                        const float* __restrict__ Wc, const float* __restrict__ bc,
                        const float* __restrict__ Wl, const float* __restrict__ bl,
                        float* __restrict__ out) {
    __shared__ float M[NP * NH];
    __shared__ float bias[NP];
    int t = threadIdx.x;
    for (int idx = t; idx < NP * NH; idx += 256) {
        int p = idx >> 7, f = idx & 127;
        float s = 0.0f;
        for (int h = 0; h < NH; ++h) s += Wl[p * NH + h] * Wc[h * NF + f];
        M[idx] = s;
    }
    if (t < NP) {
        float s = bl[t];
        for (int h = 0; h < NH; ++h) s += Wl[t * NH + h] * bc[h];
        bias[t] = s;
    }
    __syncthreads();
    for (int idx = t; idx < NG * NP; idx += 256) {
        int g = idx >> 3, p = idx & 7;
        float inv = 1.0f / fmaxf(cnt[g], 1.0f);
        float s = 0.0f;
        for (int f = 0; f < NF; ++f) s += psum[g * NF + f] * M[p * NH + f];
        out[idx] = s * inv + bias[p];
    }
}

extern "C" void kernel_launch(void* const* d_in, const int* in_sizes, int n_in,
                              void* d_out, int out_size, void* d_ws, size_t ws_size,
                              hipStream_t stream) {
    const float* x     = (const float*)d_in[0];
    const int*   ei    = (const int*)d_in[1];
    const float* ea    = (const float*)d_in[2];
    const int*   batch = (const int*)d_in[3];
    const float* Wc    = (const float*)d_in[4];
    const float* bc    = (const float*)d_in[5];
    const float* Wl    = (const float*)d_in[6];
    const float* bl    = (const float*)d_in[7];
    const int* row = ei;           // edge_index[0]
    const int* col = ei + NE;      // edge_index[1]
    float* out = (float*)d_out;

    // ---- workspace (~77.7 MB footprint, all segments 16 B aligned) ----
    // Scan scratch aliases pack (dead before k_sort writes pack).
    // Qa (bf16) = first half of H block (H dead after k_sort).
    // partial (GP*8192 f32 = 33.6 MB) = Qb half + Hd (both dead before k_pool).
    float* ws     = (float*)d_ws;
    float*  dinv   = ws;                          // NN floats            (400000 B)
    int*    rowptr = (int*)(dinv + NN);           // NN+4 ints            (400016 B)
    float*  cnt    = (float*)(rowptr + NN + 4);   // NG                   (256 B)
    float*  psum   = cnt + NG;                    // NG*NH                (32768 B)
    float2* pack   = (float2*)(psum + NG * NH);   // NE float2            (25.6 MB)
    unsigned* H    = (unsigned*)(pack + NE);      // NW*NN u32            (25.6 MB)
    float*    Hd   = (float*)(H + (size_t)NW * NN); // NW*NN f32          (25.6 MB)
    unsigned short* Qa = (unsigned short*)H;              // NN*64 bf16 (12.8 MB)
    unsigned short* Qb = Qa + (size_t)NN * NG;            // NN*64 bf16 (12.8 MB)
    float* partial = (float*)Qb;                  // GP*NG*NF f32 (33.6 MB, spans Qb+Hd)
    int* rcnt = (int*)pack;                       // scan scratch (aliases pack)
    int* px   = rcnt + SCAN_NBLK * SCAN_B;
    int* bsum = px + SCAN_NBLK * SCAN_B;
    int* bofs = bsum + SCAN_NBLK;

    const int B = 256;
    int gN  = (NN + B - 1) / B;                          // 391
    int gCW = NC * NW;                                   // 448
    int gW  = (int)(((long long)NN * 64 + B - 1) / B);   // 25000

    k_init<<<(NG * NH + B - 1) / B, B, 0, stream>>>(cnt, psum);
    k_hist<<<gCW, B, 0, stream>>>(row, H);
    k_deg_hist<<<gCW, B, 0, stream>>>(col, ea, Hd);
    k_cnt<<<gN, B, 0, stream>>>(batch, cnt);
    k_reduce<<<gN, B, 0, stream>>>(H, Hd, rcnt, dinv);

    k_scan1<<<SCAN_NBLK, SCAN_B, 0, stream>>>(rcnt, px, bsum);
    k_scan2<<<1, 64, 0, stream>>>(bsum, bofs);
    k_scan3<<<(NN + 1 + SCAN_B - 1) / SCAN_B, SCAN_B, 0, stream>>>(px, bofs, rowptr);
    k_base<<<gN, B, 0, stream>>>(rowptr, H);
    k_sort<<<gCW, B, 0, stream>>>(row, col, ea, H, dinv, pack);

    // NOTE: k_q1_gather overwrites the H region (as Qa) — H is dead after k_sort.
    k_q1_gather<<<gW, B, 0, stream>>>(rowptr, pack, batch, dinv, Qa);
    k_hop_gather<<<gW, B, 0, stream>>>(rowptr, pack, dinv, Qa, Qb);
    k_hop_gather<<<gW, B, 0, stream>>>(rowptr, pack, dinv, Qb, Qa);

    // NOTE: k_pool writes partial over Qb+Hd (dead); reads Qa (live).
    k_pool<<<GP, B, 0, stream>>>(Qa, x, partial);
    k_red<<<256, B, 0, stream>>>(partial, psum);
    k_final<<<1, B, 0, stream>>>(psum, cnt, Wc, bc, Wl, bl, out);
}